// Round 19
// baseline (2808.487 us; speedup 1.0000x reference)
//
#include <hip/hip_runtime.h>
#include <hip/hip_bf16.h>
#include <math.h>

#define HID    512
#define BATCH  256
#define TLEN   512
#define FUT    16
#define NSTEP  (TLEN + FUT)   // 528
#define NGRP   16             // batch groups
#define WPG    16             // workgroups per group (512-thread WGs)
#define BPG    16             // batch per group
#define UPW    32             // hidden units per WG
#define NR     128            // gate rows per WG (4 gates * UPW)

// workspace byte offsets (all 256-aligned)
#define OFF_W0   0u           // packed Whh0 slices  [16][128][512]  bf16 = 2 MB
#define OFF_W1   2097152u     // packed [Wih1|Whh1]  [16][128][1024] bf16 = 4 MB
#define OFF_CA   6291456u     // activations [grp(16)][p][half][b(16)][gran][u8] bf16 = 16*64KB = 1 MB
#define OFF_XF   7340032u     // feedback outs [FUT+1][256] f32
#define OFF_WI   7357440u     // Wih0 col packed [16][128] f32
#define OFF_B0   7365632u     // bih0+bhh0 packed [16][128] f32
#define OFF_B1   7373824u     // bih1+bhh1 packed [16][128] f32
#define OFF_BAR  7382016u     // 16 groups * 32 uints flag state (128B/group) = 2KB
#define OFF_XT   7384064u     // x transposed [TLEN][BATCH] f32 = 512 KB

typedef __bf16 bf16x8 __attribute__((ext_vector_type(8)));
typedef float  f32x4  __attribute__((ext_vector_type(4)));

__device__ __forceinline__ float sigf(float v)      { return 1.f / (1.f + __expf(-v)); }
__device__ __forceinline__ float tanh_fast(float v) { return 2.f / (1.f + __expf(-2.f * v)) - 1.f; }

// write-through 2B store: bypasses L2 (sc0 sc1) -> coherent at LLC
__device__ __forceinline__ void store_short_llc(void* p, unsigned short v) {
    asm volatile("global_store_short %0, %1, off sc0 sc1"
                 :: "v"(p), "v"((unsigned)v) : "memory");
}

// async global->LDS DMA, 16B/lane, aux=17 = sc0|sc1: read LLC, skip stale L2
__device__ __forceinline__ void gl2lds16_llc(const void* g, void* l) {
    __builtin_amdgcn_global_load_lds(
        (const __attribute__((address_space(1))) void*)g,
        (__attribute__((address_space(3))) void*)l, 16, 0, 17);
}

// flag-array barrier (R10-proven protocol, 16 members): per-WG relaxed
// release-slot store, wave0 polls all 16 flags lane-parallel.
__device__ __forceinline__ void flag_barrier(unsigned* flags, int m, unsigned phase) {
    __builtin_amdgcn_s_waitcnt(0);
    __syncthreads();
    if (threadIdx.x == 0)
        __hip_atomic_store(&flags[m], phase, __ATOMIC_RELAXED, __HIP_MEMORY_SCOPE_AGENT);
    if (threadIdx.x < 64) {
        const int lane = threadIdx.x;
        for (;;) {
            unsigned f = phase;
            if (lane < WPG)
                f = __hip_atomic_load(&flags[lane], __ATOMIC_RELAXED, __HIP_MEMORY_SCOPE_AGENT);
            if (__ballot(f >= phase) == ~0ull) break;
            __builtin_amdgcn_s_sleep(1);
        }
    }
    __syncthreads();
}

__global__ void lstm_init(char* __restrict__ ws, float* __restrict__ out,
                          const float* __restrict__ blin)
{
    float bl = blin[0];
    int tid = blockIdx.x * blockDim.x + threadIdx.x;
    int stride = gridDim.x * blockDim.x;
    uint4* ca = (uint4*)(ws + OFF_CA);
    for (int i = tid; i < 65536; i += stride) ca[i] = make_uint4(0u, 0u, 0u, 0u);
    float* xf = (float*)(ws + OFF_XF);
    for (int i = tid; i < (FUT + 1) * BATCH; i += stride) xf[i] = bl;
    unsigned* bar = (unsigned*)(ws + OFF_BAR);
    for (int i = tid; i < NGRP * 32; i += stride) bar[i] = 0u;
    for (int i = tid; i < BATCH * NSTEP; i += stride) out[i] = bl;
}

__global__ void lstm_pack(char* __restrict__ ws,
    const float* __restrict__ x,
    const float* __restrict__ Wih0, const float* __restrict__ Whh0,
    const float* __restrict__ bih0, const float* __restrict__ bhh0,
    const float* __restrict__ Wih1, const float* __restrict__ Whh1,
    const float* __restrict__ bih1, const float* __restrict__ bhh1)
{
    int tid = blockIdx.x * blockDim.x + threadIdx.x;
    int stride = gridDim.x * blockDim.x;

    // W0: [16][128][512], row r of slice m -> global row (r>>5)*HID + m*32 + (r&31)
    __hip_bfloat16* W0p = (__hip_bfloat16*)(ws + OFF_W0);
    for (int i = tid; i < 16 * 128 * 512; i += stride) {
        int k = i & 511, r = (i >> 9) & 127, m = i >> 16;
        int row = (r >> 5) * HID + m * UPW + (r & 31);
        W0p[i] = __float2bfloat16(Whh0[(size_t)row * HID + k]);
    }
    __hip_bfloat16* W1p = (__hip_bfloat16*)(ws + OFF_W1);
    for (int i = tid; i < 16 * 128 * 1024; i += stride) {
        int k = i & 1023, r = (i >> 10) & 127, m = i >> 17;
        int row = (r >> 5) * HID + m * UPW + (r & 31);
        float v = (k < 512) ? Wih1[(size_t)row * HID + k] : Whh1[(size_t)row * HID + (k - 512)];
        W1p[i] = __float2bfloat16(v);
    }
    float* wi = (float*)(ws + OFF_WI);
    float* b0 = (float*)(ws + OFF_B0);
    float* b1 = (float*)(ws + OFF_B1);
    for (int i = tid; i < 16 * 128; i += stride) {
        int r = i & 127, m = i >> 7;
        int row = (r >> 5) * HID + m * UPW + (r & 31);
        wi[i] = Wih0[row];                  // IN = 1
        b0[i] = bih0[row] + bhh0[row];
        b1[i] = bih1[row] + bhh1[row];
    }
    float* xT = (float*)(ws + OFF_XT);      // [T][B] for coalesced step reads
    for (int i = tid; i < TLEN * BATCH; i += stride) {
        int t = i >> 8, b = i & 255;
        xT[i] = x[(size_t)b * TLEN + t];
    }
}

__global__ __launch_bounds__(512, 2) void lstm_persist(
    const float* __restrict__ wlin,
    float* __restrict__ out, char* __restrict__ ws)
{
    const int tid  = threadIdx.x;
    const int lane = tid & 63;
    const int wave = tid >> 6;         // 0..7
    // One 512-thread WG per CU (grid=256). g=bid&15 keeps group g's members
    // at bid ≡ g (mod 8) -> XCD-local (R10/R14-confirmed placement model).
    const int g    = blockIdx.x & 15;  // group 0..15
    const int m    = blockIdx.x >> 4;  // member within group: unit slice 0..15
    const int bbase = g * BPG;

    // As: 16 rows x 2048B; row r holds [h0 gran 0..63 | h1 gran 0..63],
    // content granule c stored at granule (c + r) & 63 of its half (swizzle).
    __shared__ __attribute__((aligned(16))) __hip_bfloat16 As[16 * 1024];
    __shared__ float g0S[16][136];   // L0 gates for step t (precomputed at t-1)
    __shared__ float g1S[16][136];   // L1 gates for step t-1
    char* AsB = (char*)As;

    // zero As and g0S (t=0: h_prev=0 -> L0 gate matrix part = 0)
    {
        int* az = (int*)As;
        for (int i = tid; i < (16 * 1024 * 2) / 4; i += 512) az[i] = 0;
        float* gz = &g0S[0][0];
        for (int i = tid; i < 16 * 136; i += 512) gz[i] = 0.f;
    }

    const float* wis = (const float*)(ws + OFF_WI) + m * NR;
    const float* b0s = (const float*)(ws + OFF_B0) + m * NR;
    const float* b1s = (const float*)(ws + OFF_B1) + m * NR;
    // CA layout per group (64KB): [parity][half][b(16)][gran(64)][u8] bf16
    char* CAg = ws + OFF_CA + (size_t)g * 65536;
    float* xfeed = (float*)(ws + OFF_XF);
    const float* xT = (const float*)(ws + OFF_XT);
    unsigned* flags = (unsigned*)(ws + OFF_BAR) + g * 32;

    const int fl = lane & 15;          // n sub-index in fragment
    const int fq = lane >> 4;          // quad (k sub-chunk)
    const int w  = wave;               // wave = gate tile, 0..7 (16 rows each of NR=128)
    const int us  = tid & 31;          // unit within slice (elementwise), 0..31
    const int b0r = tid >> 5;          // batch row 0..15

    const float wl0 = wlin[m * UPW + us];
    float wiR[4], b0R[4], b1R[4];
#pragma unroll
    for (int q = 0; q < 4; ++q) {
        wiR[q] = wis[q * 32 + us];
        b0R[q] = b0s[q * 32 + us];
        b1R[q] = b1s[q * 32 + us];
    }
    float c00 = 0.f, c10 = 0.f;        // cell state regs (layer 0 / layer 1)

    // publish byte offset (within a half): content granule c = 4m + (us>>3),
    // row b -> granule (c+b)&63, plus (us&7)*2 within the 16B granule.
    const int cgr  = 4 * m + (us >> 3);
    const int pub0 = b0r * 1024 + (((cgr + b0r) & 63) << 4) + (us & 7) * 2;

    // ---- load this wave's weight slice (48 frags / 192 regs per lane) ----
    const bf16x8* W0row = (const bf16x8*)(ws + OFF_W0 + (size_t)m * NR * 512 * 2)
                          + (size_t)(w * 16 + fl) * 64;
    const bf16x8* W1row = (const bf16x8*)(ws + OFF_W1 + (size_t)m * NR * 1024 * 2)
                          + (size_t)(w * 16 + fl) * 128;
    bf16x8 w0f[16], w1f[32];
#pragma unroll
    for (int ks = 0; ks < 16; ++ks) w0f[ks] = W0row[ks * 4 + fq];
#pragma unroll
    for (int ks = 0; ks < 32; ++ks) w1f[ks] = W1row[ks * 4 + fq];

    __syncthreads();  // As/g0S zeroed before use

    const bf16x8* Asv = (const bf16x8*)As;   // 16 rows x 128 granules

    unsigned phase = 0;
    for (int t = 0; t < NSTEP; ++t) {
        const int p = t & 1;
        char* CAp = CAg + p * 32768;          // parity t:   h0(t) publish/DMA
        char* CAq = CAg + (1 - p) * 32768;    // parity t-1: h1(t-1) publish/DMA

        // ================= elementwise phase: ew0(t) + ew1(t-1) =============
        if (t >= TLEN) {
            // FUT region: ew1(t-1) atomics must be ordered before the xfeed
            // read of step t -> ew1 first, extra barrier, then ew0.
            {
                float gi = g1S[b0r][us]      + b1R[0];
                float gf = g1S[b0r][32 + us] + b1R[1];
                float gg = g1S[b0r][64 + us] + b1R[2];
                float go = g1S[b0r][96 + us] + b1R[3];
                c10 = sigf(gf) * c10 + sigf(gi) * tanh_fast(gg);
                float h = sigf(go) * tanh_fast(c10);
                __hip_bfloat16 hb = __float2bfloat16(h);
                store_short_llc(CAq + 16384 + pub0, *(unsigned short*)&hb);
                float po = wl0 * h;
#pragma unroll
                for (int off = 1; off < 32; off <<= 1) po += __shfl_xor(po, off, 64);
                if (us == 0) {
                    atomicAdd(&out[(size_t)(bbase + b0r) * NSTEP + (t - 1)], po);
                    atomicAdd(&xfeed[(t - TLEN) * BATCH + bbase + b0r], po);
                }
            }
            ++phase;
            flag_barrier(flags, m, phase);   // xfeed contributions visible
            {
                float xv0 = xfeed[(t - TLEN) * BATCH + bbase + b0r];
                float gi = g0S[b0r][us]      + b0R[0] + xv0 * wiR[0];
                float gf = g0S[b0r][32 + us] + b0R[1] + xv0 * wiR[1];
                float gg = g0S[b0r][64 + us] + b0R[2] + xv0 * wiR[2];
                float go = g0S[b0r][96 + us] + b0R[3] + xv0 * wiR[3];
                c00 = sigf(gf) * c00 + sigf(gi) * tanh_fast(gg);
                __hip_bfloat16 h = __float2bfloat16(sigf(go) * tanh_fast(c00));
                store_short_llc(CAp + pub0, *(unsigned short*)&h);
            }
        } else {
            // ew0 first: h0 publish store flies to LLC while ew1 computes.
            {
                float xv0 = xT[t * BATCH + bbase + b0r];
                float gi = g0S[b0r][us]      + b0R[0] + xv0 * wiR[0];
                float gf = g0S[b0r][32 + us] + b0R[1] + xv0 * wiR[1];
                float gg = g0S[b0r][64 + us] + b0R[2] + xv0 * wiR[2];
                float go = g0S[b0r][96 + us] + b0R[3] + xv0 * wiR[3];
                c00 = sigf(gf) * c00 + sigf(gi) * tanh_fast(gg);
                __hip_bfloat16 h = __float2bfloat16(sigf(go) * tanh_fast(c00));
                store_short_llc(CAp + pub0, *(unsigned short*)&h);
            }
            if (t > 0) {
                float gi = g1S[b0r][us]      + b1R[0];
                float gf = g1S[b0r][32 + us] + b1R[1];
                float gg = g1S[b0r][64 + us] + b1R[2];
                float go = g1S[b0r][96 + us] + b1R[3];
                c10 = sigf(gf) * c10 + sigf(gi) * tanh_fast(gg);
                float h = sigf(go) * tanh_fast(c10);
                __hip_bfloat16 hb = __float2bfloat16(h);
                store_short_llc(CAq + 16384 + pub0, *(unsigned short*)&hb);
                float po = wl0 * h;
#pragma unroll
                for (int off = 1; off < 32; off <<= 1) po += __shfl_xor(po, off, 64);
                if (us == 0)
                    atomicAdd(&out[(size_t)(bbase + b0r) * NSTEP + (t - 1)], po);
                // t-1 < TLEN-1 here -> no xfeed atomic
            }
        }

        ++phase;
        flag_barrier(flags, m, phase);   // h0(t) [+ h1(t-1)] publish -> all WGs

        // ================= stage [h0(t) | h1(t-1)] -> LDS As ================
        {
#pragma unroll
            for (int ci = 0; ci < 2; ++ci) {
                int b = wave * 2 + ci;
                gl2lds16_llc(CAp + b * 1024 + lane * 16,
                             AsB + b * 2048 + lane * 16);            // h0(t)
                gl2lds16_llc(CAq + 16384 + b * 1024 + lane * 16,
                             AsB + b * 2048 + 1024 + lane * 16);     // h1(t-1)
            }
            __builtin_amdgcn_s_waitcnt(0);
            __syncthreads();
        }

        // ================= combined GEMM phase (two lean loops) =============
        // L0 gates(t+1) = h0(t) . W0   (h0 half)
        {
            f32x4 acc = {0.f, 0.f, 0.f, 0.f};
#pragma unroll
            for (int ks = 0; ks < 16; ++ks) {
                int c = ks * 4 + fq;
                bf16x8 a0 = Asv[fl * 128 + ((c + fl) & 63)];
                acc = __builtin_amdgcn_mfma_f32_16x16x32_bf16(a0, w0f[ks], acc, 0, 0, 0);
            }
#pragma unroll
            for (int i = 0; i < 4; ++i)    // C layout: m = quad*4+reg, n = lane&15
                g0S[fq * 4 + i][w * 16 + fl] = acc[i];
        }
        // L1 gates(t) = [h0(t)|h1(t-1)] . W1   (K = 1024)
        {
            f32x4 acc = {0.f, 0.f, 0.f, 0.f};
#pragma unroll
            for (int ks = 0; ks < 16; ++ks) {        // h0 half
                int c = ks * 4 + fq;
                bf16x8 a0 = Asv[fl * 128 + ((c + fl) & 63)];
                acc = __builtin_amdgcn_mfma_f32_16x16x32_bf16(a0, w1f[ks], acc, 0, 0, 0);
            }
#pragma unroll
            for (int ks = 16; ks < 32; ++ks) {       // h1 half (granules +64)
                int c = (ks - 16) * 4 + fq;
                bf16x8 a0 = Asv[fl * 128 + 64 + ((c + fl) & 63)];
                acc = __builtin_amdgcn_mfma_f32_16x16x32_bf16(a0, w1f[ks], acc, 0, 0, 0);
            }
#pragma unroll
            for (int i = 0; i < 4; ++i)
                g1S[fq * 4 + i][w * 16 + fl] = acc[i];
        }
        __syncthreads();   // g0S/g1S writes -> next elementwise phase reads
    }

    // ================= epilogue: ew1 for the final step ====================
    {
        float gi = g1S[b0r][us]      + b1R[0];
        float gf = g1S[b0r][32 + us] + b1R[1];
        float gg = g1S[b0r][64 + us] + b1R[2];
        float go = g1S[b0r][96 + us] + b1R[3];
        c10 = sigf(gf) * c10 + sigf(gi) * tanh_fast(gg);
        float h = sigf(go) * tanh_fast(c10);
        float po = wl0 * h;
#pragma unroll
        for (int off = 1; off < 32; off <<= 1) po += __shfl_xor(po, off, 64);
        if (us == 0)
            atomicAdd(&out[(size_t)(bbase + b0r) * NSTEP + (NSTEP - 1)], po);
    }
}

extern "C" void kernel_launch(void* const* d_in, const int* in_sizes, int n_in,
                              void* d_out, int out_size, void* d_ws, size_t ws_size,
                              hipStream_t stream)
{
    const float* x    = (const float*)d_in[0];
    const float* Wih0 = (const float*)d_in[1];
    const float* Whh0 = (const float*)d_in[2];
    const float* bih0 = (const float*)d_in[3];
    const float* bhh0 = (const float*)d_in[4];
    const float* Wih1 = (const float*)d_in[5];
    const float* Whh1 = (const float*)d_in[6];
    const float* bih1 = (const float*)d_in[7];
    const float* bhh1 = (const float*)d_in[8];
    const float* Wlin = (const float*)d_in[9];
    const float* blin = (const float*)d_in[10];
    float* out = (float*)d_out;
    char* ws = (char*)d_ws;

    hipLaunchKernelGGL(lstm_init, dim3(256), dim3(256), 0, stream, ws, out, blin);
    hipLaunchKernelGGL(lstm_pack, dim3(512), dim3(256), 0, stream,
                       ws, x, Wih0, Whh0, bih0, bhh0, Wih1, Whh1, bih1, bhh1);
    hipLaunchKernelGGL(lstm_persist, dim3(256), dim3(512), 0, stream, Wlin, out, ws);
}

// Round 20
// 2355.480 us; speedup vs baseline: 1.1923x; 1.1923x over previous
//
#include <hip/hip_runtime.h>
#include <hip/hip_bf16.h>
#include <math.h>

#define HID    512
#define BATCH  256
#define TLEN   512
#define FUT    16
#define NSTEP  (TLEN + FUT)   // 528
#define NGRP   16             // batch groups
#define WPG    16             // workgroups per group (512-thread WGs)
#define BPG    16             // batch per group
#define UPW    32             // hidden units per WG
#define NR     128            // gate rows per WG (4 gates * UPW)

// workspace byte offsets (all 256-aligned)
#define OFF_W0   0u           // packed Whh0 slices  [16][128][512]  bf16 = 2 MB
#define OFF_W1   2097152u     // packed [Wih1|Whh1]  [16][128][1024] bf16 = 4 MB
#define OFF_CA   6291456u     // activations [grp(16)][p][half][b(16)][gran][u8] bf16 = 16*64KB = 1 MB
#define OFF_XF   7340032u     // feedback outs [FUT+1][256] f32
#define OFF_WI   7357440u     // Wih0 col packed [16][128] f32
#define OFF_B0   7365632u     // bih0+bhh0 packed [16][128] f32
#define OFF_B1   7373824u     // bih1+bhh1 packed [16][128] f32
#define OFF_BAR  7382016u     // 16 groups * 32 uints flag state (128B/group) = 2KB
#define OFF_XT   7384064u     // x transposed [TLEN][BATCH] f32 = 512 KB

typedef __bf16 bf16x8 __attribute__((ext_vector_type(8)));
typedef float  f32x4  __attribute__((ext_vector_type(4)));

__device__ __forceinline__ float sigf(float v)      { return 1.f / (1.f + __expf(-v)); }
__device__ __forceinline__ float tanh_fast(float v) { return 2.f / (1.f + __expf(-2.f * v)) - 1.f; }

// write-through 2B store: bypasses L2 (sc0 sc1) -> coherent at LLC
__device__ __forceinline__ void store_short_llc(void* p, unsigned short v) {
    asm volatile("global_store_short %0, %1, off sc0 sc1"
                 :: "v"(p), "v"((unsigned)v) : "memory");
}

// async global->LDS DMA, 16B/lane, aux=17 = sc0|sc1: read LLC, skip stale L2
__device__ __forceinline__ void gl2lds16_llc(const void* g, void* l) {
    __builtin_amdgcn_global_load_lds(
        (const __attribute__((address_space(1))) void*)g,
        (__attribute__((address_space(3))) void*)l, 16, 0, 17);
}

// flag-array barrier with OWN-FLAG SKIP: a WG's exit needs (a) its own
// publishes drained (waitcnt before the flag store) and (b) the OTHER 15
// WGs' flags >= phase (their data visible at LLC). It never needs to
// observe its OWN flag -- skipping lane m removes the own-store LLC
// round trip (~0.6-1.3k cyc) from the straggler's critical path.
// Others still wait on our flag exactly as before (protocol unchanged).
__device__ __forceinline__ void flag_barrier(unsigned* flags, int m, unsigned phase) {
    __builtin_amdgcn_s_waitcnt(0);
    __syncthreads();
    if (threadIdx.x == 0)
        __hip_atomic_store(&flags[m], phase, __ATOMIC_RELAXED, __HIP_MEMORY_SCOPE_AGENT);
    if (threadIdx.x < 64) {
        const int lane = threadIdx.x;
        const bool active = (lane < WPG) && (lane != m);
        for (;;) {
            unsigned f = phase;
            if (active)
                f = __hip_atomic_load(&flags[lane], __ATOMIC_RELAXED, __HIP_MEMORY_SCOPE_AGENT);
            if (__ballot(f >= phase) == ~0ull) break;
            __builtin_amdgcn_s_sleep(1);
        }
    }
    __syncthreads();
}

__global__ void lstm_init(char* __restrict__ ws, float* __restrict__ out,
                          const float* __restrict__ blin)
{
    float bl = blin[0];
    int tid = blockIdx.x * blockDim.x + threadIdx.x;
    int stride = gridDim.x * blockDim.x;
    uint4* ca = (uint4*)(ws + OFF_CA);
    for (int i = tid; i < 65536; i += stride) ca[i] = make_uint4(0u, 0u, 0u, 0u);
    float* xf = (float*)(ws + OFF_XF);
    for (int i = tid; i < (FUT + 1) * BATCH; i += stride) xf[i] = bl;
    unsigned* bar = (unsigned*)(ws + OFF_BAR);
    for (int i = tid; i < NGRP * 32; i += stride) bar[i] = 0u;
    for (int i = tid; i < BATCH * NSTEP; i += stride) out[i] = bl;
}

__global__ void lstm_pack(char* __restrict__ ws,
    const float* __restrict__ x,
    const float* __restrict__ Wih0, const float* __restrict__ Whh0,
    const float* __restrict__ bih0, const float* __restrict__ bhh0,
    const float* __restrict__ Wih1, const float* __restrict__ Whh1,
    const float* __restrict__ bih1, const float* __restrict__ bhh1)
{
    int tid = blockIdx.x * blockDim.x + threadIdx.x;
    int stride = gridDim.x * blockDim.x;

    // W0: [16][128][512], row r of slice m -> global row (r>>5)*HID + m*32 + (r&31)
    __hip_bfloat16* W0p = (__hip_bfloat16*)(ws + OFF_W0);
    for (int i = tid; i < 16 * 128 * 512; i += stride) {
        int k = i & 511, r = (i >> 9) & 127, m = i >> 16;
        int row = (r >> 5) * HID + m * UPW + (r & 31);
        W0p[i] = __float2bfloat16(Whh0[(size_t)row * HID + k]);
    }
    __hip_bfloat16* W1p = (__hip_bfloat16*)(ws + OFF_W1);
    for (int i = tid; i < 16 * 128 * 1024; i += stride) {
        int k = i & 1023, r = (i >> 10) & 127, m = i >> 17;
        int row = (r >> 5) * HID + m * UPW + (r & 31);
        float v = (k < 512) ? Wih1[(size_t)row * HID + k] : Whh1[(size_t)row * HID + (k - 512)];
        W1p[i] = __float2bfloat16(v);
    }
    float* wi = (float*)(ws + OFF_WI);
    float* b0 = (float*)(ws + OFF_B0);
    float* b1 = (float*)(ws + OFF_B1);
    for (int i = tid; i < 16 * 128; i += stride) {
        int r = i & 127, m = i >> 7;
        int row = (r >> 5) * HID + m * UPW + (r & 31);
        wi[i] = Wih0[row];                  // IN = 1
        b0[i] = bih0[row] + bhh0[row];
        b1[i] = bih1[row] + bhh1[row];
    }
    float* xT = (float*)(ws + OFF_XT);      // [T][B] for coalesced step reads
    for (int i = tid; i < TLEN * BATCH; i += stride) {
        int t = i >> 8, b = i & 255;
        xT[i] = x[(size_t)b * TLEN + t];
    }
}

__global__ __launch_bounds__(512, 2) void lstm_persist(
    const float* __restrict__ wlin,
    float* __restrict__ out, char* __restrict__ ws)
{
    const int tid  = threadIdx.x;
    const int lane = tid & 63;
    const int wave = tid >> 6;         // 0..7
    // One 512-thread WG per CU (grid=256). g=bid&15 keeps group g's members
    // at bid ≡ g (mod 8) -> XCD-local (R10/R14-confirmed placement model).
    const int g    = blockIdx.x & 15;  // group 0..15
    const int m    = blockIdx.x >> 4;  // member within group: unit slice 0..15
    const int bbase = g * BPG;

    // As: 16 rows x 2048B; row r holds [h0 gran 0..63 | h1 gran 0..63],
    // content granule c stored at granule (c + r) & 63 of its half (swizzle).
    __shared__ __attribute__((aligned(16))) __hip_bfloat16 As[16 * 1024];
    __shared__ float g0S[16][136];   // L0 gates buffer
    __shared__ float g1S[16][136];   // L1 gates buffer (split -> no tail sync)
    char* AsB = (char*)As;

    // zero As (t=0 reads h0prev=0, h1prev=0 from it)
    {
        int* az = (int*)As;
        for (int i = tid; i < (16 * 1024 * 2) / 4; i += 512) az[i] = 0;
    }

    const float* wis = (const float*)(ws + OFF_WI) + m * NR;
    const float* b0s = (const float*)(ws + OFF_B0) + m * NR;
    const float* b1s = (const float*)(ws + OFF_B1) + m * NR;
    // CA layout per group (64KB): [parity][half][b(16)][gran(64)][u8] bf16
    char* CAg = ws + OFF_CA + (size_t)g * 65536;
    float* xfeed = (float*)(ws + OFF_XF);
    const float* xT = (const float*)(ws + OFF_XT);
    unsigned* flags = (unsigned*)(ws + OFF_BAR) + g * 32;

    const int fl = lane & 15;          // n sub-index in fragment
    const int fq = lane >> 4;          // quad (k sub-chunk)
    const int w  = wave;               // wave = gate tile, 0..7 (16 rows each of NR=128)
    const int us  = tid & 31;          // unit within slice (elementwise), 0..31
    const int b0r = tid >> 5;          // batch row 0..15

    const float wl0 = wlin[m * UPW + us];
    float wiR[4], b0R[4], b1R[4];
#pragma unroll
    for (int q = 0; q < 4; ++q) {
        wiR[q] = wis[q * 32 + us];
        b0R[q] = b0s[q * 32 + us];
        b1R[q] = b1s[q * 32 + us];
    }
    float c00 = 0.f, c10 = 0.f;        // cell state regs (layer 0 / layer 1)

    // publish byte offset (within a half): content granule c = 4m + (us>>3),
    // row b -> granule (c+b)&63, plus (us&7)*2 within the 16B granule.
    const int cgr  = 4 * m + (us >> 3);
    const int pub0 = b0r * 1024 + (((cgr + b0r) & 63) << 4) + (us & 7) * 2;

    // ---- load this wave's weight slice into registers (192 regs/lane) ----
    const bf16x8* W0row = (const bf16x8*)(ws + OFF_W0 + (size_t)m * NR * 512 * 2)
                          + (size_t)(w * 16 + fl) * 64;
    const bf16x8* W1row = (const bf16x8*)(ws + OFF_W1 + (size_t)m * NR * 1024 * 2)
                          + (size_t)(w * 16 + fl) * 128;
    bf16x8 w0f[16], w1f[32];
#pragma unroll
    for (int ks = 0; ks < 16; ++ks) w0f[ks] = W0row[ks * 4 + fq];
#pragma unroll
    for (int ks = 0; ks < 32; ++ks) w1f[ks] = W1row[ks * 4 + fq];

    __syncthreads();  // As zeroed before use

    const bf16x8* Asv = (const bf16x8*)As;   // 16 rows x 128 granules

    unsigned phase = 0;
    for (int t = 0; t < NSTEP; ++t) {
        const int p = t & 1;
        char* CAp = CAg + p * 32768;          // this step's parity (h0/h1 writes)
        char* CAq = CAg + (1 - p) * 32768;    // previous parity (h1prev reads)

        float xv0;
        if (t < TLEN) {
            xv0 = xT[t * BATCH + bbase + b0r];
        } else {
            xv0 = xfeed[(t - TLEN) * BATCH + bbase + b0r];
        }

        // ---------------- layer 0 GEMM from LDS (h0prev, swizzled half 0)
        //                 (lean loop: only w0f live -> compiler pipelines reads)
        f32x4 acc0 = {0.f, 0.f, 0.f, 0.f};
#pragma unroll
        for (int ks = 0; ks < 16; ++ks) {
            int c = ks * 4 + fq;
            bf16x8 a0 = Asv[fl * 128 + ((c + fl) & 63)];
            acc0 = __builtin_amdgcn_mfma_f32_16x16x32_bf16(a0, w0f[ks], acc0, 0, 0, 0);
        }
#pragma unroll
        for (int i = 0; i < 4; ++i)    // C layout: m = quad*4+reg, n = lane&15
            g0S[fq * 4 + i][w * 16 + fl] = acc0[i];
        __syncthreads();               // sync1: g0S writes -> ew0 reads

        // ---------------- layer 0 elementwise, publish h0 via LLC
        {
            float gi = g0S[b0r][us]      + b0R[0] + xv0 * wiR[0];
            float gf = g0S[b0r][32 + us] + b0R[1] + xv0 * wiR[1];
            float gg = g0S[b0r][64 + us] + b0R[2] + xv0 * wiR[2];
            float go = g0S[b0r][96 + us] + b0R[3] + xv0 * wiR[3];
            c00 = sigf(gf) * c00 + sigf(gi) * tanh_fast(gg);
            __hip_bfloat16 h = __float2bfloat16(sigf(go) * tanh_fast(c00));
            store_short_llc(CAp + pub0, *(unsigned short*)&h);
        }

        ++phase;
        flag_barrier(flags, m, phase);   // h0(t) + h1(t-1) publish -> all WGs

        // ---------------- stage [h0new | h1prev] -> LDS As
        // fully-contiguous 1KB DMA per (row, half): global gran == LDS gran
        {
#pragma unroll
            for (int ci = 0; ci < 2; ++ci) {
                int b = wave * 2 + ci;
                gl2lds16_llc(CAp + b * 1024 + lane * 16,
                             AsB + b * 2048 + lane * 16);            // h0 new
                gl2lds16_llc(CAq + 16384 + b * 1024 + lane * 16,
                             AsB + b * 2048 + 1024 + lane * 16);     // h1 prev
            }
            __builtin_amdgcn_s_waitcnt(0);
            __syncthreads();             // sync2: DMA -> L1 reads
        }

        // ---------------- layer 1 GEMM: K=1024 over [h0new | h1prev]
        acc0 = (f32x4){0.f, 0.f, 0.f, 0.f};
#pragma unroll
        for (int ks = 0; ks < 16; ++ks) {        // h0 half
            int c = ks * 4 + fq;
            bf16x8 a0 = Asv[fl * 128 + ((c + fl) & 63)];
            acc0 = __builtin_amdgcn_mfma_f32_16x16x32_bf16(a0, w1f[ks], acc0, 0, 0, 0);
        }
#pragma unroll
        for (int ks = 16; ks < 32; ++ks) {       // h1 half (granules +64)
            int c = (ks - 16) * 4 + fq;
            bf16x8 a0 = Asv[fl * 128 + 64 + ((c + fl) & 63)];
            acc0 = __builtin_amdgcn_mfma_f32_16x16x32_bf16(a0, w1f[ks], acc0, 0, 0, 0);
        }
#pragma unroll
        for (int i = 0; i < 4; ++i)
            g1S[fq * 4 + i][w * 16 + fl] = acc0[i];
        __syncthreads();               // sync3: g1S writes -> ew1 reads

        // ---------------- layer 1 elementwise + OUT=1 linear, publish h1 via LLC
        {
            float gi = g1S[b0r][us]      + b1R[0];
            float gf = g1S[b0r][32 + us] + b1R[1];
            float gg = g1S[b0r][64 + us] + b1R[2];
            float go = g1S[b0r][96 + us] + b1R[3];
            c10 = sigf(gf) * c10 + sigf(gi) * tanh_fast(gg);
            float h = sigf(go) * tanh_fast(c10);
            __hip_bfloat16 hb = __float2bfloat16(h);
            store_short_llc(CAp + 16384 + pub0, *(unsigned short*)&hb);
            float po = wl0 * h;
#pragma unroll
            for (int off = 1; off < 32; off <<= 1) po += __shfl_xor(po, off, 64);
            if (us == 0) {
                atomicAdd(&out[(size_t)(bbase + b0r) * NSTEP + t], po);
                if (t >= TLEN - 1)
                    atomicAdd(&xfeed[(t - (TLEN - 1)) * BATCH + bbase + b0r], po);
            }
        }

        // No tail __syncthreads: g0S/g1S are separate buffers; every remaining
        // cross-iteration hazard is ordered by sync1/sync2/sync3 or the next
        // flag_barrier's internal syncs. FUT region still needs the barrier
        // to order xfeed atomics -> next step's feedback reads.
        if (t >= TLEN - 1) {
            ++phase;
            flag_barrier(flags, m, phase);
        }
    }
}

extern "C" void kernel_launch(void* const* d_in, const int* in_sizes, int n_in,
                              void* d_out, int out_size, void* d_ws, size_t ws_size,
                              hipStream_t stream)
{
    const float* x    = (const float*)d_in[0];
    const float* Wih0 = (const float*)d_in[1];
    const float* Whh0 = (const float*)d_in[2];
    const float* bih0 = (const float*)d_in[3];
    const float* bhh0 = (const float*)d_in[4];
    const float* Wih1 = (const float*)d_in[5];
    const float* Whh1 = (const float*)d_in[6];
    const float* bih1 = (const float*)d_in[7];
    const float* bhh1 = (const float*)d_in[8];
    const float* Wlin = (const float*)d_in[9];
    const float* blin = (const float*)d_in[10];
    float* out = (float*)d_out;
    char* ws = (char*)d_ws;

    hipLaunchKernelGGL(lstm_init, dim3(256), dim3(256), 0, stream, ws, out, blin);
    hipLaunchKernelGGL(lstm_pack, dim3(512), dim3(256), 0, stream,
                       ws, x, Wih0, Whh0, bih0, bhh0, Wih1, Whh1, bih1, bhh1);
    hipLaunchKernelGGL(lstm_persist, dim3(256), dim3(512), 0, stream, Wlin, out, ws);
}